// Round 1
// 224.893 us; speedup vs baseline: 1.0829x; 1.0829x over previous
//
#include <hip/hip_runtime.h>
#include <hip/hip_bf16.h>
#include <hip/hip_fp16.h>

// GNN layer: out = segment_sum(edge_vals * h[edge_cols], edge_rows), h = x @ W
// N=100000 nodes, E=1.6M edges, D=128.
//
// R6: bucket_accum was latency-bound at 28% occupancy (grid 782 blocks x 4
// waves = 3128 waves vs 8192 slots; scattered 256B LLC-latency gathers with
// too few waves to hide them; VALUBusy 26%, hbm 32%). Split each bucket's
// pass-2 across SPLIT=4 blocks of 32 rows each: grid -> 3128 blocks, LDS
// 23.5KB -> ~12.5KB, occupancy cap -> 100%. Each sub-block re-reads the whole
// (LLC-resident) bucket region; scan shrinks to a 1-wave shuffle scan.
// Pass 1 / GEMM / repack unchanged from R5 for clean attribution.

#define DIM 128
#define RB 128        // rows per bucket (pass-1 partition granularity)
#define NB_MAX 1024   // max buckets supported by pass1 LDS arrays
#define CH 4096       // edges per pass1 block
#define REG_CAP 2560  // records per bucket region (mean 2048, +11 sigma)

#define SPLIT 4           // pass-2 blocks per bucket
#define RSUB (RB / SPLIT) // rows per pass-2 block = 32
#define SRT_CAP 1536      // records per sub-block (mean 512, huge margin)

typedef short s16x8 __attribute__((ext_vector_type(8)));
typedef float f32x4 __attribute__((ext_vector_type(4)));
typedef unsigned short u16;
typedef unsigned long long u64;
typedef u16 u16x4 __attribute__((ext_vector_type(4)));
typedef u16 u16x8 __attribute__((ext_vector_type(8)));

static __device__ __forceinline__ u16 f2bf(float f) {
  union { float f; unsigned u; } a; a.f = f;
  return (u16)((a.u + 0x7fffu + ((a.u >> 16) & 1u)) >> 16);
}
static __device__ __forceinline__ float bf_lo(unsigned u) {
  union { unsigned u; float f; } a; a.u = u << 16; return a.f;
}
static __device__ __forceinline__ float bf_hi(unsigned u) {
  union { unsigned u; float f; } a; a.u = u & 0xffff0000u; return a.f;
}
static __device__ __forceinline__ u16 f2h(float f) {
  return __half_as_ushort(__float2half(f));
}
static __device__ __forceinline__ float h2f(u16 h) {
  return __half2float(__ushort_as_half(h));
}

// ---------------- W repack: fp32 [k][n] -> bf16 B-fragment order ----------------
__global__ __launch_bounds__(256) void repack_w_kernel(
    const float* __restrict__ W, u16* __restrict__ Wp) {
  int e = blockIdx.x * 256 + threadIdx.x;  // 0..16383
  int k = e >> 7, n = e & 127;
  Wp[((k >> 3) * 128 + n) * 8 + (k & 7)] = f2bf(W[e]);
}

// ---------------- bf16 MFMA GEMM: h = x @ W (unchanged) ----------------
__global__ __launch_bounds__(256) void mfma_gemm_kernel(
    const float* __restrict__ x, const u16* __restrict__ Wp,
    u16* __restrict__ hb, int n_nodes) {
  __shared__ u16 xl[128 * 136];
  const int t = threadIdx.x;
  const int m0 = blockIdx.x * 128;

  const float4* x4 = (const float4*)x;
#pragma unroll
  for (int it = 0; it < 16; ++it) {
    int i = it * 256 + t;
    int r = i >> 5, c = i & 31;
    float4 v = make_float4(0.f, 0.f, 0.f, 0.f);
    int node = m0 + r;
    if (node < n_nodes) v = x4[(size_t)node * 32 + c];
    u16x4 pk = {f2bf(v.x), f2bf(v.y), f2bf(v.z), f2bf(v.w)};
    *(u16x4*)&xl[r * 136 + c * 4] = pk;
  }
  __syncthreads();

  const int w = t >> 6, l = t & 63, q = l >> 4, n15 = l & 15;

  f32x4 acc[2][8];
#pragma unroll
  for (int mt = 0; mt < 2; ++mt)
#pragma unroll
    for (int nt = 0; nt < 8; ++nt) acc[mt][nt] = (f32x4){0.f, 0.f, 0.f, 0.f};

#pragma unroll
  for (int ks = 0; ks < 4; ++ks) {
    s16x8 a0 = *(const s16x8*)&xl[(w * 32 + n15) * 136 + ks * 32 + q * 8];
    s16x8 a1 = *(const s16x8*)&xl[(w * 32 + 16 + n15) * 136 + ks * 32 + q * 8];
#pragma unroll
    for (int nt = 0; nt < 8; ++nt) {
      s16x8 b = *(const s16x8*)&Wp[(size_t)(((ks * 4 + q) * 128) + nt * 16 + n15) * 8];
      acc[0][nt] = __builtin_amdgcn_mfma_f32_16x16x32_bf16(a0, b, acc[0][nt], 0, 0, 0);
      acc[1][nt] = __builtin_amdgcn_mfma_f32_16x16x32_bf16(a1, b, acc[1][nt], 0, 0, 0);
    }
  }
  __syncthreads();

#pragma unroll
  for (int mt = 0; mt < 2; ++mt)
#pragma unroll
    for (int nt = 0; nt < 8; ++nt)
#pragma unroll
      for (int r_ = 0; r_ < 4; ++r_)
        xl[(w * 32 + mt * 16 + q * 4 + r_) * 136 + nt * 16 + n15] =
            f2bf(acc[mt][nt][r_]);
  __syncthreads();

#pragma unroll
  for (int it = 0; it < 8; ++it) {
    int chunk = it * 256 + t;
    int r = chunk >> 4, c = chunk & 15;
    int node = m0 + r;
    if (node < n_nodes)
      *(u16x8*)(hb + (size_t)node * 128 + c * 8) = *(const u16x8*)&xl[r * 136 + c * 8];
  }
}

// ---------------- pass 1: partition edges into row-buckets (unchanged) ----------------
// LDS: srec 32KB + 4x4KB int arrays + tsum 1KB = ~50KB
__global__ __launch_bounds__(256) void part_kernel(
    const int* __restrict__ rows, const int* __restrict__ cols,
    const float* __restrict__ vals, int* __restrict__ gcur,
    u64* __restrict__ reg, int n_edges, int nb) {
  __shared__ int hist[NB_MAX];
  __shared__ int ofs[NB_MAX];
  __shared__ int gbase[NB_MAX];
  __shared__ int lcur[NB_MAX];
  __shared__ int tsum[256];
  __shared__ u64 srec[CH];

  const int t = threadIdx.x;
  const int base = blockIdx.x * CH;

  for (int i = t; i < NB_MAX; i += 256) { hist[i] = 0; lcur[i] = 0; }
  __syncthreads();

  // load 16 edges/thread (stride-256 coalesced), LDS histogram
  int r[16], c[16];
  float v[16];
  bool ok[16];
#pragma unroll
  for (int i = 0; i < 16; ++i) {
    int e = base + i * 256 + t;
    ok[i] = e < n_edges;
    r[i] = ok[i] ? rows[e] : 0;
    c[i] = ok[i] ? cols[e] : 0;
    v[i] = ok[i] ? vals[e] : 0.f;
    if (ok[i]) atomicAdd(&hist[r[i] >> 7], 1);
  }
  __syncthreads();

  // exclusive scan over NB_MAX (4/thread + Hillis over 256)
  const int b0 = t * 4;
  int h0 = hist[b0], h1 = hist[b0 + 1], h2 = hist[b0 + 2], h3 = hist[b0 + 3];
  int run = h0 + h1 + h2 + h3;
  tsum[t] = run;
  // reserve global space per bucket (coalesced atomics; independent of scan)
  for (int b = t; b < nb; b += 256) {
    int hc = hist[b];
    gbase[b] = (hc > 0) ? atomicAdd(&gcur[b], hc) : 0;
  }
  __syncthreads();
  for (int off = 1; off < 256; off <<= 1) {
    int x = (t >= off) ? tsum[t - off] : 0;
    __syncthreads();
    tsum[t] += x;
    __syncthreads();
  }
  int ex = tsum[t] - run;
  ofs[b0] = ex;
  ofs[b0 + 1] = ex + h0;
  ofs[b0 + 2] = ex + h0 + h1;
  ofs[b0 + 3] = ex + h0 + h1 + h2;
  __syncthreads();

  // scatter records into bucket-sorted LDS order
#pragma unroll
  for (int i = 0; i < 16; ++i) {
    if (ok[i]) {
      int bkt = r[i] >> 7;
      int pos = ofs[bkt] + atomicAdd(&lcur[bkt], 1);
      srec[pos] = ((u64)(unsigned)r[i] << 33) | ((u64)(unsigned)c[i] << 16) |
                  (u64)f2h(v[i]);
    }
  }
  __syncthreads();

  // coalesced-run write to global bucket regions
  int nvalid = n_edges - base;
  if (nvalid > CH) nvalid = CH;
  for (int i = t; i < nvalid; i += 256) {
    u64 rec = srec[i];
    int row = (int)(rec >> 33);
    int bkt = row >> 7;
    int dst = gbase[bkt] + (i - ofs[bkt]);
    if (dst < REG_CAP) reg[(size_t)bkt * REG_CAP + dst] = rec;
  }
}

// ---------------- pass 2: per-sub-bucket group-by-row + gather-accumulate ----------------
// R6: SPLIT=4 blocks per bucket, each owns RSUB=32 rows.
// LDS: srt 12KB + 3x128B = ~12.5KB -> occupancy wave-limited (8 blocks/CU).
__global__ __launch_bounds__(256) void bucket_accum_kernel(
    const u16* __restrict__ hb, const u64* __restrict__ reg,
    const int* __restrict__ gcur, float* __restrict__ out, int n_nodes) {
  __shared__ int hist[RSUB];
  __shared__ int ofs[RSUB];
  __shared__ int lcur[RSUB];
  __shared__ u64 srt[SRT_CAP];

  const int t = threadIdx.x;
  const int b = blockIdx.x / SPLIT;    // bucket
  const int sub = blockIdx.x % SPLIT;  // row sub-range within bucket
  const int rl0 = sub * RSUB;          // local row base
  const int row0 = b * RB + rl0;       // global row base of this block

  int n_e = gcur[b];
  if (n_e > REG_CAP) n_e = REG_CAP;

  if (t < RSUB) { hist[t] = 0; lcur[t] = 0; }
  __syncthreads();

  // load whole bucket region (coalesced, LLC-resident), keep only our rows
  u64 rr[10];
  int rl[10];
  bool ok[10];
#pragma unroll
  for (int i = 0; i < 10; ++i) {
    int j = i * 256 + t;
    ok[i] = j < n_e;
    rr[i] = ok[i] ? reg[(size_t)b * REG_CAP + j] : 0;
    rl[i] = ((int)(rr[i] >> 33) & (RB - 1)) - rl0;
    ok[i] = ok[i] && ((unsigned)rl[i] < (unsigned)RSUB);
    if (ok[i]) atomicAdd(&hist[rl[i]], 1);
  }
  __syncthreads();

  // exclusive scan of RSUB=32 entries: single-wave shuffle scan
  if (t < 64) {
    int hv = (t < RSUB) ? hist[t] : 0;
    int v = hv;
#pragma unroll
    for (int off = 1; off < RSUB; off <<= 1) {
      int u = __shfl_up(v, off, 64);
      if (t >= off) v += u;
    }
    if (t < RSUB) ofs[t] = v - hv;  // exclusive prefix
  }
  __syncthreads();

  // scatter our records into row-sorted LDS order
#pragma unroll
  for (int i = 0; i < 10; ++i) {
    if (ok[i]) {
      int pos = ofs[rl[i]] + atomicAdd(&lcur[rl[i]], 1);
      if (pos < SRT_CAP) srt[pos] = rr[i];
    }
  }
  __syncthreads();

  // wave-per-row accumulate: wave w owns rows [w*8, w*8+8) of this sub-range
  const int lane = t & 63;
  const int w = t >> 6;
  const unsigned* h32 = (const unsigned*)hb;
  float2* out2 = (float2*)out;

  for (int k = 0; k < RSUB / 4; ++k) {
    int rli = w * (RSUB / 4) + k;
    int gr = row0 + rli;
    if (gr >= n_nodes) continue;
    int s = ofs[rli];
    int n = hist[rli];
    if (s + n > SRT_CAP) n = SRT_CAP - s;  // paranoia guard (matches pass-1 drop policy)
    if (n < 0) n = 0;
    float2 acc = make_float2(0.f, 0.f);
    int i = 0;
    for (; i + 8 <= n; i += 8) {
      unsigned uu[8];
      float vv[8];
#pragma unroll
      for (int j = 0; j < 8; ++j) {
        u64 rec = srt[s + i + j];
        int col = (int)((rec >> 16) & 0x1FFFF);
        vv[j] = h2f((u16)(rec & 0xFFFF));
        uu[j] = h32[(size_t)col * 64 + lane];
      }
#pragma unroll
      for (int j = 0; j < 8; ++j) {
        acc.x += vv[j] * bf_lo(uu[j]);
        acc.y += vv[j] * bf_hi(uu[j]);
      }
    }
    for (; i < n; ++i) {
      u64 rec = srt[s + i];
      int col = (int)((rec >> 16) & 0x1FFFF);
      float vv = h2f((u16)(rec & 0xFFFF));
      unsigned uu = h32[(size_t)col * 64 + lane];
      acc.x += vv * bf_lo(uu);
      acc.y += vv * bf_hi(uu);
    }
    out2[(size_t)gr * 64 + lane] = acc;
  }
}

// ---------------- fallback (atomic scatter on bf16 h) ----------------
__global__ __launch_bounds__(256) void scatter_kernel(
    const u16* __restrict__ hb, const float* __restrict__ vals,
    const int* __restrict__ rows, const int* __restrict__ cols,
    float* __restrict__ out, int n_edges) {
  const int lane = threadIdx.x & 63;
  const int wid = (blockIdx.x * blockDim.x + threadIdx.x) >> 6;
  const int nwaves = (gridDim.x * blockDim.x) >> 6;
  const unsigned* h32 = (const unsigned*)hb;
  for (int e = wid; e < n_edges; e += nwaves) {
    int r = rows[e];
    int c = cols[e];
    float v = vals[e];
    unsigned u = h32[(size_t)c * 64 + lane];
    float* op = out + (size_t)r * DIM + 2 * lane;
    atomicAdd(op, v * bf_lo(u));
    atomicAdd(op + 1, v * bf_hi(u));
  }
}

extern "C" void kernel_launch(void* const* d_in, const int* in_sizes, int n_in,
                              void* d_out, int out_size, void* d_ws, size_t ws_size,
                              hipStream_t stream) {
  const float* x = (const float*)d_in[0];
  const float* W = (const float*)d_in[1];
  const float* edge_vals = (const float*)d_in[2];
  const int* edge_rows = (const int*)d_in[3];
  const int* edge_cols = (const int*)d_in[4];
  float* out = (float*)d_out;

  const int n_nodes = in_sizes[0] / DIM;
  const int n_edges = in_sizes[2];
  const int nb = (n_nodes + RB - 1) / RB;

  // ws layout (16B-aligned chunks)
  char* p = (char*)d_ws;
  u16* hb = (u16*)p;   p += (((size_t)n_nodes * DIM * 2 + 15) / 16) * 16;  // 25.6 MB
  u16* Wp = (u16*)p;   p += (size_t)DIM * DIM * 2;                         // 32 KB
  int* gcur = (int*)p; p += (((size_t)nb * 4 + 15) / 16) * 16;             // ~3 KB
  u64* reg = (u64*)p;  p += (size_t)nb * REG_CAP * 8;                      // ~16 MB
  const size_t need = (size_t)(p - (char*)d_ws);

  repack_w_kernel<<<64, 256, 0, stream>>>(W, Wp);
  mfma_gemm_kernel<<<(n_nodes + 127) / 128, 256, 0, stream>>>(x, Wp, hb, n_nodes);

  if (ws_size < need || nb > NB_MAX) {
    hipMemsetAsync(d_out, 0, (size_t)out_size * sizeof(float), stream);
    scatter_kernel<<<2048, 256, 0, stream>>>(hb, edge_vals, edge_rows, edge_cols,
                                             out, n_edges);
    return;
  }

  hipMemsetAsync(gcur, 0, (size_t)nb * sizeof(int), stream);

  int p1_blocks = (n_edges + CH - 1) / CH;
  part_kernel<<<p1_blocks, 256, 0, stream>>>(edge_rows, edge_cols, edge_vals,
                                             gcur, reg, n_edges, nb);

  bucket_accum_kernel<<<nb * SPLIT, 256, 0, stream>>>(hb, reg, gcur, out, n_nodes);
}

// Round 2
// 224.481 us; speedup vs baseline: 1.0849x; 1.0018x over previous
//
#include <hip/hip_runtime.h>
#include <hip/hip_bf16.h>
#include <hip/hip_fp16.h>

// GNN layer: out = segment_sum(edge_vals * h[edge_cols], edge_rows), h = x @ W
// N=100000 nodes, E=1.6M edges, D=128.
//
// R7: R6's SPLIT=4 pass-2 bought occupancy (28->62%) but quadrupled region
// decode work: 3128 sub-blocks x 2048 records = 6.4M load+decode events vs
// 1.6M useful -> ~44us of pure VALU issue (matches VALUBusy 36% @ 72us).
// Replace with ONE 1024-thread (16-wave) block per bucket: same 32-wave/CU
// occupancy cap (2 blocks/CU, LDS 22KB), but each region is read+decoded
// exactly once. Scan shrinks to a single-wave shuffle scan (2 entries/lane);
// wave w owns rows [8w, 8w+8). GEMM / pass 1 / repack unchanged.

#define DIM 128
#define RB 128        // rows per bucket (pass-1 partition granularity)
#define NB_MAX 1024   // max buckets supported by pass1 LDS arrays
#define CH 4096       // edges per pass1 block
#define REG_CAP 2560  // records per bucket region (mean 2048, +11 sigma)

typedef short s16x8 __attribute__((ext_vector_type(8)));
typedef float f32x4 __attribute__((ext_vector_type(4)));
typedef unsigned short u16;
typedef unsigned long long u64;
typedef u16 u16x4 __attribute__((ext_vector_type(4)));
typedef u16 u16x8 __attribute__((ext_vector_type(8)));

static __device__ __forceinline__ u16 f2bf(float f) {
  union { float f; unsigned u; } a; a.f = f;
  return (u16)((a.u + 0x7fffu + ((a.u >> 16) & 1u)) >> 16);
}
static __device__ __forceinline__ float bf_lo(unsigned u) {
  union { unsigned u; float f; } a; a.u = u << 16; return a.f;
}
static __device__ __forceinline__ float bf_hi(unsigned u) {
  union { unsigned u; float f; } a; a.u = u & 0xffff0000u; return a.f;
}
static __device__ __forceinline__ u16 f2h(float f) {
  return __half_as_ushort(__float2half(f));
}
static __device__ __forceinline__ float h2f(u16 h) {
  return __half2float(__ushort_as_half(h));
}

// ---------------- W repack: fp32 [k][n] -> bf16 B-fragment order ----------------
__global__ __launch_bounds__(256) void repack_w_kernel(
    const float* __restrict__ W, u16* __restrict__ Wp) {
  int e = blockIdx.x * 256 + threadIdx.x;  // 0..16383
  int k = e >> 7, n = e & 127;
  Wp[((k >> 3) * 128 + n) * 8 + (k & 7)] = f2bf(W[e]);
}

// ---------------- bf16 MFMA GEMM: h = x @ W (unchanged) ----------------
__global__ __launch_bounds__(256) void mfma_gemm_kernel(
    const float* __restrict__ x, const u16* __restrict__ Wp,
    u16* __restrict__ hb, int n_nodes) {
  __shared__ u16 xl[128 * 136];
  const int t = threadIdx.x;
  const int m0 = blockIdx.x * 128;

  const float4* x4 = (const float4*)x;
#pragma unroll
  for (int it = 0; it < 16; ++it) {
    int i = it * 256 + t;
    int r = i >> 5, c = i & 31;
    float4 v = make_float4(0.f, 0.f, 0.f, 0.f);
    int node = m0 + r;
    if (node < n_nodes) v = x4[(size_t)node * 32 + c];
    u16x4 pk = {f2bf(v.x), f2bf(v.y), f2bf(v.z), f2bf(v.w)};
    *(u16x4*)&xl[r * 136 + c * 4] = pk;
  }
  __syncthreads();

  const int w = t >> 6, l = t & 63, q = l >> 4, n15 = l & 15;

  f32x4 acc[2][8];
#pragma unroll
  for (int mt = 0; mt < 2; ++mt)
#pragma unroll
    for (int nt = 0; nt < 8; ++nt) acc[mt][nt] = (f32x4){0.f, 0.f, 0.f, 0.f};

#pragma unroll
  for (int ks = 0; ks < 4; ++ks) {
    s16x8 a0 = *(const s16x8*)&xl[(w * 32 + n15) * 136 + ks * 32 + q * 8];
    s16x8 a1 = *(const s16x8*)&xl[(w * 32 + 16 + n15) * 136 + ks * 32 + q * 8];
#pragma unroll
    for (int nt = 0; nt < 8; ++nt) {
      s16x8 b = *(const s16x8*)&Wp[(size_t)(((ks * 4 + q) * 128) + nt * 16 + n15) * 8];
      acc[0][nt] = __builtin_amdgcn_mfma_f32_16x16x32_bf16(a0, b, acc[0][nt], 0, 0, 0);
      acc[1][nt] = __builtin_amdgcn_mfma_f32_16x16x32_bf16(a1, b, acc[1][nt], 0, 0, 0);
    }
  }
  __syncthreads();

#pragma unroll
  for (int mt = 0; mt < 2; ++mt)
#pragma unroll
    for (int nt = 0; nt < 8; ++nt)
#pragma unroll
      for (int r_ = 0; r_ < 4; ++r_)
        xl[(w * 32 + mt * 16 + q * 4 + r_) * 136 + nt * 16 + n15] =
            f2bf(acc[mt][nt][r_]);
  __syncthreads();

#pragma unroll
  for (int it = 0; it < 8; ++it) {
    int chunk = it * 256 + t;
    int r = chunk >> 4, c = chunk & 15;
    int node = m0 + r;
    if (node < n_nodes)
      *(u16x8*)(hb + (size_t)node * 128 + c * 8) = *(const u16x8*)&xl[r * 136 + c * 8];
  }
}

// ---------------- pass 1: partition edges into row-buckets (unchanged) ----------------
// LDS: srec 32KB + 4x4KB int arrays + tsum 1KB = ~50KB
__global__ __launch_bounds__(256) void part_kernel(
    const int* __restrict__ rows, const int* __restrict__ cols,
    const float* __restrict__ vals, int* __restrict__ gcur,
    u64* __restrict__ reg, int n_edges, int nb) {
  __shared__ int hist[NB_MAX];
  __shared__ int ofs[NB_MAX];
  __shared__ int gbase[NB_MAX];
  __shared__ int lcur[NB_MAX];
  __shared__ int tsum[256];
  __shared__ u64 srec[CH];

  const int t = threadIdx.x;
  const int base = blockIdx.x * CH;

  for (int i = t; i < NB_MAX; i += 256) { hist[i] = 0; lcur[i] = 0; }
  __syncthreads();

  // load 16 edges/thread (stride-256 coalesced), LDS histogram
  int r[16], c[16];
  float v[16];
  bool ok[16];
#pragma unroll
  for (int i = 0; i < 16; ++i) {
    int e = base + i * 256 + t;
    ok[i] = e < n_edges;
    r[i] = ok[i] ? rows[e] : 0;
    c[i] = ok[i] ? cols[e] : 0;
    v[i] = ok[i] ? vals[e] : 0.f;
    if (ok[i]) atomicAdd(&hist[r[i] >> 7], 1);
  }
  __syncthreads();

  // exclusive scan over NB_MAX (4/thread + Hillis over 256)
  const int b0 = t * 4;
  int h0 = hist[b0], h1 = hist[b0 + 1], h2 = hist[b0 + 2], h3 = hist[b0 + 3];
  int run = h0 + h1 + h2 + h3;
  tsum[t] = run;
  // reserve global space per bucket (coalesced atomics; independent of scan)
  for (int b = t; b < nb; b += 256) {
    int hc = hist[b];
    gbase[b] = (hc > 0) ? atomicAdd(&gcur[b], hc) : 0;
  }
  __syncthreads();
  for (int off = 1; off < 256; off <<= 1) {
    int x = (t >= off) ? tsum[t - off] : 0;
    __syncthreads();
    tsum[t] += x;
    __syncthreads();
  }
  int ex = tsum[t] - run;
  ofs[b0] = ex;
  ofs[b0 + 1] = ex + h0;
  ofs[b0 + 2] = ex + h0 + h1;
  ofs[b0 + 3] = ex + h0 + h1 + h2;
  __syncthreads();

  // scatter records into bucket-sorted LDS order
#pragma unroll
  for (int i = 0; i < 16; ++i) {
    if (ok[i]) {
      int bkt = r[i] >> 7;
      int pos = ofs[bkt] + atomicAdd(&lcur[bkt], 1);
      srec[pos] = ((u64)(unsigned)r[i] << 33) | ((u64)(unsigned)c[i] << 16) |
                  (u64)f2h(v[i]);
    }
  }
  __syncthreads();

  // coalesced-run write to global bucket regions
  int nvalid = n_edges - base;
  if (nvalid > CH) nvalid = CH;
  for (int i = t; i < nvalid; i += 256) {
    u64 rec = srec[i];
    int row = (int)(rec >> 33);
    int bkt = row >> 7;
    int dst = gbase[bkt] + (i - ofs[bkt]);
    if (dst < REG_CAP) reg[(size_t)bkt * REG_CAP + dst] = rec;
  }
}

// ---------------- pass 2: per-bucket group-by-row + gather-accumulate ----------------
// R7: 1024 threads (16 waves) per bucket. LDS: srt 20KB + 3x512B = ~22KB.
// Occupancy cap: 2 blocks/CU x 16 waves = 32 waves/CU (100%); region decoded once.
__global__ __launch_bounds__(1024) void bucket_accum_kernel(
    const u16* __restrict__ hb, const u64* __restrict__ reg,
    const int* __restrict__ gcur, float* __restrict__ out, int n_nodes) {
  __shared__ int hist[RB];
  __shared__ int ofs[RB];
  __shared__ int lcur[RB];
  __shared__ u64 srt[REG_CAP];

  const int t = threadIdx.x;
  const int b = blockIdx.x;
  const int row0 = b * RB;

  int n_e = gcur[b];
  if (n_e > REG_CAP) n_e = REG_CAP;

  if (t < RB) { hist[t] = 0; lcur[t] = 0; }
  __syncthreads();

  // load region once (coalesced, LLC-resident), histogram by local row
  u64 rr[3];
  int rl[3];
  bool ok[3];
#pragma unroll
  for (int i = 0; i < 3; ++i) {
    int j = i * 1024 + t;
    ok[i] = j < n_e;
    rr[i] = ok[i] ? reg[(size_t)b * REG_CAP + j] : 0;
    rl[i] = (int)(rr[i] >> 33) & (RB - 1);
    if (ok[i]) atomicAdd(&hist[rl[i]], 1);
  }
  __syncthreads();

  // exclusive scan of RB=128 entries by wave 0: 2 entries/lane shuffle scan
  if (t < 64) {
    int h0 = hist[2 * t], h1 = hist[2 * t + 1];
    int s = h0 + h1;
    int v = s;
#pragma unroll
    for (int off = 1; off < 64; off <<= 1) {
      int u = __shfl_up(v, off, 64);
      if (t >= off) v += u;
    }
    int ex = v - s;  // exclusive prefix of pair-sums
    ofs[2 * t] = ex;
    ofs[2 * t + 1] = ex + h0;
  }
  __syncthreads();

  // scatter records into row-sorted LDS order (pos < n_e <= REG_CAP by construction)
#pragma unroll
  for (int i = 0; i < 3; ++i) {
    if (ok[i]) {
      int pos = ofs[rl[i]] + atomicAdd(&lcur[rl[i]], 1);
      srt[pos] = rr[i];
    }
  }
  __syncthreads();

  // wave-per-row accumulate: wave w owns rows [w*8, w*8+8)
  const int lane = t & 63;
  const int w = t >> 6;  // 0..15
  const unsigned* h32 = (const unsigned*)hb;
  float2* out2 = (float2*)out;

  for (int k = 0; k < RB / 16; ++k) {
    int rli = w * (RB / 16) + k;
    int gr = row0 + rli;
    if (gr >= n_nodes) continue;
    int s = ofs[rli];
    int n = hist[rli];
    float2 acc = make_float2(0.f, 0.f);
    int i = 0;
    for (; i + 8 <= n; i += 8) {
      unsigned uu[8];
      float vv[8];
#pragma unroll
      for (int j = 0; j < 8; ++j) {
        u64 rec = srt[s + i + j];
        int col = (int)((rec >> 16) & 0x1FFFF);
        vv[j] = h2f((u16)(rec & 0xFFFF));
        uu[j] = h32[(size_t)col * 64 + lane];
      }
#pragma unroll
      for (int j = 0; j < 8; ++j) {
        acc.x += vv[j] * bf_lo(uu[j]);
        acc.y += vv[j] * bf_hi(uu[j]);
      }
    }
    for (; i < n; ++i) {
      u64 rec = srt[s + i];
      int col = (int)((rec >> 16) & 0x1FFFF);
      float vv = h2f((u16)(rec & 0xFFFF));
      unsigned uu = h32[(size_t)col * 64 + lane];
      acc.x += vv * bf_lo(uu);
      acc.y += vv * bf_hi(uu);
    }
    out2[(size_t)gr * 64 + lane] = acc;
  }
}

// ---------------- fallback (atomic scatter on bf16 h) ----------------
__global__ __launch_bounds__(256) void scatter_kernel(
    const u16* __restrict__ hb, const float* __restrict__ vals,
    const int* __restrict__ rows, const int* __restrict__ cols,
    float* __restrict__ out, int n_edges) {
  const int lane = threadIdx.x & 63;
  const int wid = (blockIdx.x * blockDim.x + threadIdx.x) >> 6;
  const int nwaves = (gridDim.x * blockDim.x) >> 6;
  const unsigned* h32 = (const unsigned*)hb;
  for (int e = wid; e < n_edges; e += nwaves) {
    int r = rows[e];
    int c = cols[e];
    float v = vals[e];
    unsigned u = h32[(size_t)c * 64 + lane];
    float* op = out + (size_t)r * DIM + 2 * lane;
    atomicAdd(op, v * bf_lo(u));
    atomicAdd(op + 1, v * bf_hi(u));
  }
}

extern "C" void kernel_launch(void* const* d_in, const int* in_sizes, int n_in,
                              void* d_out, int out_size, void* d_ws, size_t ws_size,
                              hipStream_t stream) {
  const float* x = (const float*)d_in[0];
  const float* W = (const float*)d_in[1];
  const float* edge_vals = (const float*)d_in[2];
  const int* edge_rows = (const int*)d_in[3];
  const int* edge_cols = (const int*)d_in[4];
  float* out = (float*)d_out;

  const int n_nodes = in_sizes[0] / DIM;
  const int n_edges = in_sizes[2];
  const int nb = (n_nodes + RB - 1) / RB;

  // ws layout (16B-aligned chunks)
  char* p = (char*)d_ws;
  u16* hb = (u16*)p;   p += (((size_t)n_nodes * DIM * 2 + 15) / 16) * 16;  // 25.6 MB
  u16* Wp = (u16*)p;   p += (size_t)DIM * DIM * 2;                         // 32 KB
  int* gcur = (int*)p; p += (((size_t)nb * 4 + 15) / 16) * 16;             // ~3 KB
  u64* reg = (u64*)p;  p += (size_t)nb * REG_CAP * 8;                      // ~16 MB
  const size_t need = (size_t)(p - (char*)d_ws);

  repack_w_kernel<<<64, 256, 0, stream>>>(W, Wp);
  mfma_gemm_kernel<<<(n_nodes + 127) / 128, 256, 0, stream>>>(x, Wp, hb, n_nodes);

  if (ws_size < need || nb > NB_MAX) {
    hipMemsetAsync(d_out, 0, (size_t)out_size * sizeof(float), stream);
    scatter_kernel<<<2048, 256, 0, stream>>>(hb, edge_vals, edge_rows, edge_cols,
                                             out, n_edges);
    return;
  }

  hipMemsetAsync(gcur, 0, (size_t)nb * sizeof(int), stream);

  int p1_blocks = (n_edges + CH - 1) / CH;
  part_kernel<<<p1_blocks, 256, 0, stream>>>(edge_rows, edge_cols, edge_vals,
                                             gcur, reg, n_edges, nb);

  bucket_accum_kernel<<<nb, 1024, 0, stream>>>(hb, reg, gcur, out, n_nodes);
}